// Round 2
// baseline (1230.328 us; speedup 1.0000x reference)
//
#include <hip/hip_runtime.h>
#include <hip/hip_bf16.h>
#include <stdint.h>

typedef __attribute__((ext_vector_type(8))) short short8;
typedef __attribute__((ext_vector_type(4))) float float4v;

#define NEG_SLOPE 0.01f
#define LDS_S 136  // h-tile row stride (elems): mult of 8 for 16B-aligned ds_read_b128

__device__ __forceinline__ float bf2f(uint16_t u) {
    union { uint32_t i; float f; } c; c.i = ((uint32_t)u) << 16; return c.f;
}
__device__ __forceinline__ uint16_t f2bf(float f) {
    union { float ff; uint32_t i; } c; c.ff = f;
    uint32_t x = c.i;
    x += 0x7fffu + ((x >> 16) & 1u);   // RNE
    return (uint16_t)(x >> 16);
}
__device__ __forceinline__ float ldf(const void* p, int idx, int isf32) {
    return isf32 ? ((const float*)p)[idx] : bf2f(((const uint16_t*)p)[idx]);
}

// ---------- dtype probe: fp32 weights have sane fp32 exponents; bf16 pairs don't ----------
__global__ __launch_bounds__(64) void detect_dtype(const uint32_t* __restrict__ bits,
                                                   int* __restrict__ flag) {
    int t = threadIdx.x;
    int sane = 0;
    #pragma unroll
    for (int i = 0; i < 4; ++i) {
        uint32_t u = bits[t * 4 + i];
        uint32_t e = (u >> 23) & 0xffu;
        sane += (e >= 64u && e <= 150u) ? 1 : 0;  // fp32 N(0,0.09): e~118..126. bf16-pair view: e~230..250
    }
    #pragma unroll
    for (int off = 32; off > 0; off >>= 1) sane += __shfl_down(sane, off, 64);
    if (t == 0) *flag = (sane >= 128) ? 1 : 0;   // 1 = inputs are fp32
}

// ---------- pack W1/W2 into MFMA B-fragment order ----------
// B-frag (16x16x32): lane holds B[k=(lane>>4)*8+j][n=lane&15], j=0..7
__global__ __launch_bounds__(256) void pack_w(
    const void* __restrict__ W1, const void* __restrict__ W2,
    const int* __restrict__ flag,
    uint16_t* __restrict__ W1p, uint16_t* __restrict__ W2p)
{
    int isf32 = *flag;
    int pid = blockIdx.x * 256 + threadIdx.x;
    if (pid < 20480) {                       // W1: 8 ct * 5 kc * 64 * 8
        int j = pid & 7, lane = (pid >> 3) & 63, rest = pid >> 9;
        int kc = rest % 5, ct = rest / 5;
        int k = kc * 32 + (lane >> 4) * 8 + j;
        int n = ct * 16 + (lane & 15);
        W1p[pid] = f2bf(ldf(W1, k * 128 + n, isf32));
    }
    int pid2 = pid - 20480;
    if (pid2 >= 0 && pid2 < 16384) {         // W2: 8 ct * 4 kc * 64 * 8
        int j = pid2 & 7, lane = (pid2 >> 3) & 63, rest = pid2 >> 9;
        int kc = rest & 3, ct = rest >> 2;
        int k = kc * 32 + (lane >> 4) * 8 + j;
        int n = ct * 16 + (lane & 15);
        W2p[pid2] = f2bf(ldf(W2, k * 128 + n, isf32));
    }
}

// ---------- scatter: edge_attr -> per-node fp32 sums + counts ----------
__global__ __launch_bounds__(256) void scatter_kernel(
    const void* __restrict__ ea, const int* __restrict__ eidx,
    const int* __restrict__ flag, int E,
    float* __restrict__ rec_sum, float* __restrict__ sent_sum,
    float* __restrict__ rec_cnt, float* __restrict__ sent_cnt)
{
    int isf32 = *flag;
    int gid = blockIdx.x * 256 + threadIdx.x;
    int e = gid >> 3;
    if (e >= E) return;
    int dp = gid & 7;                      // pair of dims 2*dp, 2*dp+1
    float f0, f1;
    if (isf32) {
        const float* p = (const float*)ea + (size_t)e * 16 + dp * 2;
        f0 = p[0]; f1 = p[1];
    } else {
        uint32_t v = ((const uint32_t*)ea)[gid];
        f0 = bf2f((uint16_t)(v & 0xffffu));
        f1 = bf2f((uint16_t)(v >> 16));
    }
    int row = eidx[e];
    int col = eidx[E + e];
    int d = dp * 2;
    unsafeAtomicAdd(rec_sum + row * 16 + d, f0);
    unsafeAtomicAdd(rec_sum + row * 16 + d + 1, f1);
    unsafeAtomicAdd(sent_sum + col * 16 + d, f0);
    unsafeAtomicAdd(sent_sum + col * 16 + d + 1, f1);
    if (dp == 0) {
        unsafeAtomicAdd(rec_cnt + row, 1.0f);
        unsafeAtomicAdd(sent_cnt + col, 1.0f);
    }
}

// ---------- fused MLP: [x|rec_mean|sent_mean] @ W1 -> leaky -> @ W2 ----------
// block = 256 = 4 waves; wave handles 16 nodes x 128 cols via 16x16x32 bf16 MFMA
__global__ __launch_bounds__(256) void mlp_kernel(
    const void* __restrict__ x,           // [N,128] fp32 or bf16
    const float* __restrict__ rec_sum, const float* __restrict__ sent_sum,
    const float* __restrict__ rec_cnt, const float* __restrict__ sent_cnt,
    const uint16_t* __restrict__ W1p, const uint16_t* __restrict__ W2p,
    const void* __restrict__ b1, const void* __restrict__ b2,
    const int* __restrict__ flag,
    void* __restrict__ out, int N)
{
    __shared__ alignas(16) uint16_t hbuf[4 * 16 * LDS_S];
    int isf32 = *flag;
    int wave = threadIdx.x >> 6;
    int lane = threadIdx.x & 63;
    int m = lane & 15, q = lane >> 4;
    int nw = blockIdx.x * 64 + wave * 16;
    int node = nw + m;
    int nclamp = node < N ? node : N - 1;

    // A fragments: A[m=lane&15][k=q*8+j]; d_in = 160 = 5 K-chunks of 32
    short8 afr[5];
    if (isf32) {
        const float* xf = (const float*)x + (size_t)nclamp * 128;
        #pragma unroll
        for (int kc = 0; kc < 4; ++kc) {
            const float* p = xf + kc * 32 + q * 8;
            short8 a;
            #pragma unroll
            for (int j = 0; j < 8; ++j) a[j] = (short)f2bf(p[j]);
            afr[kc] = a;
        }
    } else {
        const uint16_t* xh = (const uint16_t*)x + (size_t)nclamp * 128;
        #pragma unroll
        for (int kc = 0; kc < 4; ++kc)
            afr[kc] = *(const short8*)(xh + kc * 32 + q * 8);
    }
    {   // chunk 4: k=128..159 -> [rec_mean(16) | sent_mean(16)]
        const float* msrc = (q < 2) ? (rec_sum + (size_t)nclamp * 16 + q * 8)
                                    : (sent_sum + (size_t)nclamp * 16 + (q - 2) * 8);
        float cnt = (q < 2) ? rec_cnt[nclamp] : sent_cnt[nclamp];
        cnt = cnt < 1.f ? 1.f : cnt;
        float inv = 1.0f / cnt;
        short8 a;
        #pragma unroll
        for (int j = 0; j < 8; ++j) a[j] = (short)f2bf(msrc[j] * inv);
        afr[4] = a;
    }

    uint16_t* hw = hbuf + wave * 16 * LDS_S;

    // GEMM1 + bias + LeakyReLU -> LDS (bf16)
    #pragma unroll
    for (int ct = 0; ct < 8; ++ct) {
        float4v acc = {0.f, 0.f, 0.f, 0.f};
        #pragma unroll
        for (int kc = 0; kc < 5; ++kc) {
            short8 bfr = *(const short8*)(W1p + ((ct * 5 + kc) * 64 + lane) * 8);
            acc = __builtin_amdgcn_mfma_f32_16x16x32_bf16(afr[kc], bfr, acc, 0, 0, 0);
        }
        int c = ct * 16 + m;                 // C/D: col = lane&15, row = q*4+r
        float bias = ldf(b1, c, isf32);
        #pragma unroll
        for (int r = 0; r < 4; ++r) {
            float h = acc[r] + bias;
            h = h >= 0.f ? h : NEG_SLOPE * h;
            hw[(q * 4 + r) * LDS_S + c] = f2bf(h);
        }
    }
    __syncthreads();

    // A2 fragments of h from LDS
    short8 a2[4];
    #pragma unroll
    for (int kc = 0; kc < 4; ++kc)
        a2[kc] = *(const short8*)(hw + m * LDS_S + kc * 32 + q * 8);

    // GEMM2 + bias -> out
    #pragma unroll
    for (int ct = 0; ct < 8; ++ct) {
        float4v acc = {0.f, 0.f, 0.f, 0.f};
        #pragma unroll
        for (int kc = 0; kc < 4; ++kc) {
            short8 bfr = *(const short8*)(W2p + ((ct * 4 + kc) * 64 + lane) * 8);
            acc = __builtin_amdgcn_mfma_f32_16x16x32_bf16(a2[kc], bfr, acc, 0, 0, 0);
        }
        int c = ct * 16 + m;
        float bias = ldf(b2, c, isf32);
        #pragma unroll
        for (int r = 0; r < 4; ++r) {
            int onode = nw + q * 4 + r;
            if (onode < N) {
                float v = acc[r] + bias;
                size_t idx = (size_t)onode * 128 + c;
                if (isf32) ((float*)out)[idx] = v;
                else       ((uint16_t*)out)[idx] = f2bf(v);
            }
        }
    }
}

extern "C" void kernel_launch(void* const* d_in, const int* in_sizes, int n_in,
                              void* d_out, int out_size, void* d_ws, size_t ws_size,
                              hipStream_t stream) {
    const void* x   = d_in[0];
    const int* eidx = (const int*)d_in[1];
    const void* ea  = d_in[2];
    const void* W1  = d_in[3];
    const void* b1  = d_in[4];
    const void* W2  = d_in[5];
    const void* b2  = d_in[6];
    int N = in_sizes[0] / 128;
    int E = in_sizes[1] / 2;

    float* rec_sum  = (float*)d_ws;                    // N*16
    float* sent_sum = rec_sum + (size_t)N * 16;        // N*16
    float* rec_cnt  = sent_sum + (size_t)N * 16;       // N
    float* sent_cnt = rec_cnt + N;                     // N
    int*   flag     = (int*)(sent_cnt + N);            // 1 (pad 16B)
    uint16_t* W1p   = (uint16_t*)(flag + 4);           // 20480 bf16
    uint16_t* W2p   = W1p + 20480;                     // 16384 bf16

    // zero sums + counts (ws is poisoned 0xAA before each call)
    size_t zero_bytes = ((size_t)N * 32 + 2 * (size_t)N) * sizeof(float);
    hipMemsetAsync(d_ws, 0, zero_bytes, stream);

    detect_dtype<<<1, 64, 0, stream>>>((const uint32_t*)W2, flag);

    pack_w<<<(20480 + 16384 + 255) / 256, 256, 0, stream>>>(W1, W2, flag, W1p, W2p);

    int sblocks = (E * 8 + 255) / 256;
    scatter_kernel<<<sblocks, 256, 0, stream>>>(ea, eidx, flag, E,
                                                rec_sum, sent_sum, rec_cnt, sent_cnt);

    mlp_kernel<<<(N + 63) / 64, 256, 0, stream>>>(x, rec_sum, sent_sum, rec_cnt, sent_cnt,
                                                  W1p, W2p, b1, b2, flag, out_size ? d_out : d_out, N);
}

// Round 3
// 912.016 us; speedup vs baseline: 1.3490x; 1.3490x over previous
//
#include <hip/hip_runtime.h>
#include <hip/hip_bf16.h>
#include <hip/hip_fp16.h>
#include <stdint.h>

typedef __attribute__((ext_vector_type(8))) short short8;
typedef __attribute__((ext_vector_type(4))) float float4v;

#define NEG_SLOPE 0.01f
#define LDS_S 136  // h-tile row stride (elems): mult of 8 for 16B-aligned ds_read_b128

__device__ __forceinline__ float bf2f(uint16_t u) {
    union { uint32_t i; float f; } c; c.i = ((uint32_t)u) << 16; return c.f;
}
__device__ __forceinline__ uint16_t f2bf(float f) {
    union { float ff; uint32_t i; } c; c.ff = f;
    uint32_t x = c.i;
    x += 0x7fffu + ((x >> 16) & 1u);   // RNE
    return (uint16_t)(x >> 16);
}

// ---------- pack W1/W2 (fp32) into bf16 MFMA B-fragment order ----------
// B-frag (16x16x32): lane holds B[k=(lane>>4)*8+j][n=lane&15], j=0..7
__global__ __launch_bounds__(256) void pack_w(
    const float* __restrict__ W1, const float* __restrict__ W2,
    uint16_t* __restrict__ W1p, uint16_t* __restrict__ W2p)
{
    int pid = blockIdx.x * 256 + threadIdx.x;
    if (pid < 20480) {                       // W1: 8 ct * 5 kc * 64 * 8
        int j = pid & 7, lane = (pid >> 3) & 63, rest = pid >> 9;
        int kc = rest % 5, ct = rest / 5;
        int k = kc * 32 + (lane >> 4) * 8 + j;
        int n = ct * 16 + (lane & 15);
        W1p[pid] = f2bf(W1[k * 128 + n]);
    }
    int pid2 = pid - 20480;
    if (pid2 >= 0 && pid2 < 16384) {         // W2: 8 ct * 4 kc * 64 * 8
        int j = pid2 & 7, lane = (pid2 >> 3) & 63, rest = pid2 >> 9;
        int kc = rest & 3, ct = rest >> 2;
        int k = kc * 32 + (lane >> 4) * 8 + j;
        int n = ct * 16 + (lane & 15);
        W2p[pid2] = f2bf(W2[k * 128 + n]);
    }
}

// ---------- scatter: edge_attr (fp32) -> per-node fp16 sums + fp32 counts ----------
// 8 threads per edge, each owns dim pair (2*dp, 2*dp+1); one pk_add_f16 per array.
__global__ __launch_bounds__(256) void scatter_kernel(
    const float* __restrict__ ea, const int* __restrict__ eidx, int E,
    __half* __restrict__ rec_sum, __half* __restrict__ sent_sum,
    float* __restrict__ rec_cnt, float* __restrict__ sent_cnt)
{
    int gid = blockIdx.x * 256 + threadIdx.x;
    int e = gid >> 3;
    if (e >= E) return;
    int dp = gid & 7;
    const float* p = ea + (size_t)e * 16 + dp * 2;
    __half2 h = __floats2half2_rn(p[0], p[1]);
    int row = eidx[e];
    int col = eidx[E + e];
    unsafeAtomicAdd((__half2*)(rec_sum + row * 16 + dp * 2), h);
    unsafeAtomicAdd((__half2*)(sent_sum + col * 16 + dp * 2), h);
    if (dp == 0) {
        unsafeAtomicAdd(rec_cnt + row, 1.0f);
        unsafeAtomicAdd(sent_cnt + col, 1.0f);
    }
}

// ---------- fused MLP: [x|rec_mean|sent_mean] @ W1 -> leaky -> @ W2 ----------
// block = 256 = 4 waves; wave handles 16 nodes x 128 cols via 16x16x32 bf16 MFMA
__global__ __launch_bounds__(256) void mlp_kernel(
    const float* __restrict__ x,          // [N,128] fp32
    const __half* __restrict__ rec_sum, const __half* __restrict__ sent_sum,
    const float* __restrict__ rec_cnt, const float* __restrict__ sent_cnt,
    const uint16_t* __restrict__ W1p, const uint16_t* __restrict__ W2p,
    const float* __restrict__ b1, const float* __restrict__ b2,
    float* __restrict__ out, int N)
{
    __shared__ alignas(16) uint16_t hbuf[4 * 16 * LDS_S];
    int wave = threadIdx.x >> 6;
    int lane = threadIdx.x & 63;
    int m = lane & 15, q = lane >> 4;
    int nw = blockIdx.x * 64 + wave * 16;
    int node = nw + m;
    int nclamp = node < N ? node : N - 1;

    // A fragments: A[m=lane&15][k=q*8+j]; d_in = 160 = 5 K-chunks of 32
    short8 afr[5];
    {
        const float* xf = x + (size_t)nclamp * 128;
        #pragma unroll
        for (int kc = 0; kc < 4; ++kc) {
            float4 v0 = *(const float4*)(xf + kc * 32 + q * 8);
            float4 v1 = *(const float4*)(xf + kc * 32 + q * 8 + 4);
            short8 a;
            a[0] = (short)f2bf(v0.x); a[1] = (short)f2bf(v0.y);
            a[2] = (short)f2bf(v0.z); a[3] = (short)f2bf(v0.w);
            a[4] = (short)f2bf(v1.x); a[5] = (short)f2bf(v1.y);
            a[6] = (short)f2bf(v1.z); a[7] = (short)f2bf(v1.w);
            afr[kc] = a;
        }
    }
    {   // chunk 4: k=128..159 -> [rec_mean(16) | sent_mean(16)]
        const __half* msrc = (q < 2) ? (rec_sum + (size_t)nclamp * 16 + q * 8)
                                     : (sent_sum + (size_t)nclamp * 16 + (q - 2) * 8);
        float cnt = (q < 2) ? rec_cnt[nclamp] : sent_cnt[nclamp];
        cnt = cnt < 1.f ? 1.f : cnt;
        float inv = 1.0f / cnt;
        short8 a;
        #pragma unroll
        for (int jj = 0; jj < 4; ++jj) {
            __half2 hv = *(const __half2*)(msrc + jj * 2);
            float2 fv = __half22float2(hv);
            a[jj * 2]     = (short)f2bf(fv.x * inv);
            a[jj * 2 + 1] = (short)f2bf(fv.y * inv);
        }
        afr[4] = a;
    }

    uint16_t* hw = hbuf + wave * 16 * LDS_S;

    // GEMM1 + bias + LeakyReLU -> LDS (bf16)
    #pragma unroll
    for (int ct = 0; ct < 8; ++ct) {
        float4v acc = {0.f, 0.f, 0.f, 0.f};
        #pragma unroll
        for (int kc = 0; kc < 5; ++kc) {
            short8 bfr = *(const short8*)(W1p + ((ct * 5 + kc) * 64 + lane) * 8);
            acc = __builtin_amdgcn_mfma_f32_16x16x32_bf16(afr[kc], bfr, acc, 0, 0, 0);
        }
        int c = ct * 16 + m;                 // C/D: col = lane&15, row = q*4+r
        float bias = b1[c];
        #pragma unroll
        for (int r = 0; r < 4; ++r) {
            float h = acc[r] + bias;
            h = h >= 0.f ? h : NEG_SLOPE * h;
            hw[(q * 4 + r) * LDS_S + c] = f2bf(h);
        }
    }
    __syncthreads();

    // A2 fragments of h from LDS
    short8 a2[4];
    #pragma unroll
    for (int kc = 0; kc < 4; ++kc)
        a2[kc] = *(const short8*)(hw + m * LDS_S + kc * 32 + q * 8);

    // GEMM2 + bias -> out (fp32)
    #pragma unroll
    for (int ct = 0; ct < 8; ++ct) {
        float4v acc = {0.f, 0.f, 0.f, 0.f};
        #pragma unroll
        for (int kc = 0; kc < 4; ++kc) {
            short8 bfr = *(const short8*)(W2p + ((ct * 4 + kc) * 64 + lane) * 8);
            acc = __builtin_amdgcn_mfma_f32_16x16x32_bf16(a2[kc], bfr, acc, 0, 0, 0);
        }
        int c = ct * 16 + m;
        float bias = b2[c];
        #pragma unroll
        for (int r = 0; r < 4; ++r) {
            int onode = nw + q * 4 + r;
            if (onode < N)
                out[(size_t)onode * 128 + c] = acc[r] + bias;
        }
    }
}

extern "C" void kernel_launch(void* const* d_in, const int* in_sizes, int n_in,
                              void* d_out, int out_size, void* d_ws, size_t ws_size,
                              hipStream_t stream) {
    const float* x   = (const float*)d_in[0];
    const int* eidx  = (const int*)d_in[1];
    const float* ea  = (const float*)d_in[2];
    const float* W1  = (const float*)d_in[3];
    const float* b1  = (const float*)d_in[4];
    const float* W2  = (const float*)d_in[5];
    const float* b2  = (const float*)d_in[6];
    float* out = (float*)d_out;
    int N = in_sizes[0] / 128;
    int E = in_sizes[1] / 2;

    __half* rec_sum  = (__half*)d_ws;                       // N*16 fp16
    __half* sent_sum = rec_sum + (size_t)N * 16;            // N*16 fp16
    float* rec_cnt   = (float*)(sent_sum + (size_t)N * 16); // N fp32
    float* sent_cnt  = rec_cnt + N;                         // N fp32
    uint16_t* W1p    = (uint16_t*)(sent_cnt + N);           // 20480 bf16
    uint16_t* W2p    = W1p + 20480;                         // 16384 bf16

    // zero sums (fp16 zero = 0x0000) + counts; ws is poisoned 0xAA before each call
    size_t zero_bytes = (size_t)N * 32 * sizeof(__half) + (size_t)2 * N * sizeof(float);
    hipMemsetAsync(d_ws, 0, zero_bytes, stream);

    pack_w<<<(20480 + 16384 + 255) / 256, 256, 0, stream>>>(W1, W2, W1p, W2p);

    int sblocks = (E * 8 + 255) / 256;
    scatter_kernel<<<sblocks, 256, 0, stream>>>(ea, eidx, E,
                                                rec_sum, sent_sum, rec_cnt, sent_cnt);

    mlp_kernel<<<(N + 63) / 64, 256, 0, stream>>>(x, rec_sum, sent_sum, rec_cnt, sent_cnt,
                                                  W1p, W2p, b1, b2, out, N);
}